// Round 4
// baseline (394.891 us; speedup 1.0000x reference)
//
#include <hip/hip_runtime.h>
#include <math.h>

#define B 16
#define C 128
#define H 32
#define W 512

// ---------------- Kernel A: grouped (1x3) conv, groups=2, LDS-staged ----------------
// One block per (group, h, b). 512 threads = 8 waves; wave = otile*2 + half;
// thread tile 16 o x 4 w. x AND weights staged in LDS in 4 ci-chunks of 16,
// so the inner loop is pure ds_read + FMA (no SMEM -> no lgkmcnt(0) drains).
// Fused: pool over W (-> pool3) and per-group partial pool over C (-> pool1p).
__global__ __launch_bounds__(512, 4) void conv_grouped_lds(
    const float* __restrict__ x, const float* __restrict__ wg,
    float* __restrict__ y, float* __restrict__ pool3, float* __restrict__ pool1p) {
    // xs row: [4 zeros][512 data][4 zeros]
    __shared__ __align__(16) float xs[16][520];    // 33,280 B (reused as pc after loop)
    __shared__ __align__(16) float wlds[16][196];  // 12,544 B  [ci][o*3+tap]
    __shared__ float pw[8][16][2];                 // 1 KB

    const int g = blockIdx.x;
    const int h = blockIdx.y;
    const int b = blockIdx.z;
    const int t = threadIdx.x;
    const int lane = t & 63;
    const int wave = t >> 6;                                   // 0..7
    const int half = wave & 1;
    const int o_base = __builtin_amdgcn_readfirstlane(wave >> 1) * 16;  // SGPR
    const int w0 = (half << 8) + lane * 4;

    if (t < 16) {                                              // zero halos (persist)
        *(float4*)&xs[t][0]   = make_float4(0.f, 0.f, 0.f, 0.f);
        *(float4*)&xs[t][516] = make_float4(0.f, 0.f, 0.f, 0.f);
    }

    float acc[16][4];
#pragma unroll
    for (int i = 0; i < 16; ++i)
#pragma unroll
        for (int j = 0; j < 4; ++j) acc[i][j] = 0.f;

    for (int chunk = 0; chunk < 4; ++chunk) {
        __syncthreads();
        // ---- stage x: 16 rows; wave stages rows wave*2(+1), direct global->LDS ----
#pragma unroll
        for (int rr = 0; rr < 2; ++rr) {
            const int r = wave * 2 + rr;
            const float* xrow =
                x + ((size_t)(b * C + g * 64 + chunk * 16 + r) * H + h) * W;
            __builtin_amdgcn_global_load_lds(
                (const __attribute__((address_space(1))) void*)(xrow + lane * 4),
                (__attribute__((address_space(3))) void*)&xs[r][4], 16, 0, 0);
            __builtin_amdgcn_global_load_lds(
                (const __attribute__((address_space(1))) void*)(xrow + 256 + lane * 4),
                (__attribute__((address_space(3))) void*)&xs[r][260], 16, 0, 0);
        }
        // ---- stage weights: [16ci][64o][3] = 3072 floats ----
        for (int idx = t; idx < 3072; idx += 512) {
            const int o   = idx / 48;
            const int r2  = idx - o * 48;
            const int cil = r2 / 3;
            const int tap = r2 - cil * 3;
            wlds[cil][o * 3 + tap] =
                wg[((size_t)(g * 64 + o) * 64 + chunk * 16 + cil) * 3 + tap];
        }
        __syncthreads();
        // ---- compute: pure LDS inner loop ----
#pragma unroll 2
        for (int ci = 0; ci < 16; ++ci) {
            const float4 D = *(const float4*)&xs[ci][w0];      // x[w0-4..w0-1]
            const float4 E = *(const float4*)&xs[ci][w0 + 4];  // x[w0..w0+3]
            const float4 F = *(const float4*)&xs[ci][w0 + 8];  // x[w0+4..w0+7]
#pragma unroll
            for (int og = 0; og < 4; ++og) {
                float4 wq[3];
                wq[0] = *(const float4*)&wlds[ci][o_base * 3 + og * 12];
                wq[1] = *(const float4*)&wlds[ci][o_base * 3 + og * 12 + 4];
                wq[2] = *(const float4*)&wlds[ci][o_base * 3 + og * 12 + 8];
                const float* wf = (const float*)wq;
#pragma unroll
                for (int i2 = 0; i2 < 4; ++i2) {
                    const int i = og * 4 + i2;
                    const float k0 = wf[i2 * 3 + 0];
                    const float k1 = wf[i2 * 3 + 1];
                    const float k2 = wf[i2 * 3 + 2];
                    acc[i][0] += D.w * k0 + E.x * k1 + E.y * k2;
                    acc[i][1] += E.x * k0 + E.y * k1 + E.z * k2;
                    acc[i][2] += E.y * k0 + E.z * k1 + E.w * k2;
                    acc[i][3] += E.z * k0 + E.w * k1 + F.x * k2;
                }
            }
        }
    }

    // store y
#pragma unroll
    for (int i = 0; i < 16; ++i)
        *(float4*)(y + ((size_t)(b * C + g * 64 + o_base + i) * H + h) * W + w0) =
            make_float4(acc[i][0], acc[i][1], acc[i][2], acc[i][3]);

    __syncthreads();                       // xs no longer needed; reuse for pc
    float* pc = (float*)xs;                // [8][64][4][2] = 16 KB

    // ---- pool over W (per-channel m/s across this row) ----
    {
        float wm[16], wsv[16];
#pragma unroll
        for (int i = 0; i < 16; ++i) {
            wm[i]  = fmaxf(fmaxf(acc[i][0], acc[i][1]), fmaxf(acc[i][2], acc[i][3]));
            wsv[i] = acc[i][0] + acc[i][1] + acc[i][2] + acc[i][3];
        }
#pragma unroll
        for (int off = 32; off; off >>= 1)
#pragma unroll
            for (int i = 0; i < 16; ++i) {
                wm[i]  = fmaxf(wm[i], __shfl_xor(wm[i], off));
                wsv[i] += __shfl_xor(wsv[i], off);
            }
        if (lane == 0)
#pragma unroll
            for (int i = 0; i < 16; ++i) {
                pw[wave][i][0] = wm[i];
                pw[wave][i][1] = wsv[i];
            }
    }
    // ---- partial pool over C (this block's 64 channels) ----
    {
        float cm[4], csv[4];
#pragma unroll
        for (int j = 0; j < 4; ++j) { cm[j] = acc[0][j]; csv[j] = acc[0][j]; }
#pragma unroll
        for (int i = 1; i < 16; ++i)
#pragma unroll
            for (int j = 0; j < 4; ++j) {
                cm[j]  = fmaxf(cm[j], acc[i][j]);
                csv[j] += acc[i][j];
            }
#pragma unroll
        for (int j = 0; j < 4; ++j) {
            pc[(wave * 64 + lane) * 8 + j * 2 + 0] = cm[j];
            pc[(wave * 64 + lane) * 8 + j * 2 + 1] = csv[j];
        }
    }
    __syncthreads();

    if (t < 64) {                          // pool_w combine: c = g*64 + t
        const int ot = t >> 4, i = t & 15;
        const float m0 = fmaxf(pw[2 * ot][i][0], pw[2 * ot + 1][i][0]);
        const float s0 = (pw[2 * ot][i][1] + pw[2 * ot + 1][i][1]) * (1.f / W);
        const int c = g * 64 + ot * 16 + i;
        pool3[((size_t)(b * 2 + 0) * H + h) * C + c] = m0;
        pool3[((size_t)(b * 2 + 1) * H + h) * C + c] = s0;
    }
    {                                      // pool_c partial combine over 4 otiles
        const int hf = t >> 8, l2 = (t >> 2) & 63, j = t & 3;
        const int w = (hf << 8) + l2 * 4 + j;
        float m0 = -INFINITY, s0 = 0.f;
#pragma unroll
        for (int ot = 0; ot < 4; ++ot) {
            const int idx = ((ot * 2 + hf) * 64 + l2) * 8 + j * 2;
            m0 = fmaxf(m0, pc[idx]);
            s0 += pc[idx + 1];
        }
        pool1p[((size_t)(g * B + b) * 2 + 0) * (H * W) + h * W + w] = m0;
        pool1p[((size_t)(g * B + b) * 2 + 1) * (H * W) + h * W + w] = s0;
    }
}

// ---------------- combine pool1 partials (2 groups) -> pool1 [B,2,H,W] ----------------
__global__ __launch_bounds__(256) void combine_pool1(const float* __restrict__ p1p,
                                                     float* __restrict__ pool1) {
    const int n = blockIdx.x * 256 + threadIdx.x;   // over B*H*W/4
    const int b = n >> 12;
    const int o = (n & 4095) * 4;                   // h*W+w offset
    const float4 m0 = *(const float4*)(p1p + ((size_t)(0 * B + b) * 2 + 0) * (H * W) + o);
    const float4 m1 = *(const float4*)(p1p + ((size_t)(1 * B + b) * 2 + 0) * (H * W) + o);
    const float4 s0 = *(const float4*)(p1p + ((size_t)(0 * B + b) * 2 + 1) * (H * W) + o);
    const float4 s1 = *(const float4*)(p1p + ((size_t)(1 * B + b) * 2 + 1) * (H * W) + o);
    float4 mo, so;
    mo.x = fmaxf(m0.x, m1.x); mo.y = fmaxf(m0.y, m1.y);
    mo.z = fmaxf(m0.z, m1.z); mo.w = fmaxf(m0.w, m1.w);
    const float k = 1.f / C;
    so.x = (s0.x + s1.x) * k; so.y = (s0.y + s1.y) * k;
    so.z = (s0.z + s1.z) * k; so.w = (s0.w + s1.w) * k;
    *(float4*)(pool1 + ((size_t)(b * 2 + 0) * H * W) + o) = mo;
    *(float4*)(pool1 + ((size_t)(b * 2 + 1) * H * W) + o) = so;
}

// ---------------- pool over H -> [B,2,C,W], float4 ----------------
__global__ __launch_bounds__(256) void pool_h(const float* __restrict__ y,
                                              float* __restrict__ pool2) {
    const int n  = blockIdx.x * 256 + threadIdx.x;  // over B*C*(W/4)
    const int b  = n >> 14;
    const int c  = (n >> 7) & 127;
    const int w0 = (n & 127) << 2;
    const float* p = y + ((size_t)(b * C + c) * H) * W + w0;
    float4 m = *(const float4*)p;
    float4 s = m;
    for (int hh = 1; hh < H; ++hh) {
        const float4 v = *(const float4*)(p + (size_t)hh * W);
        m.x = fmaxf(m.x, v.x); m.y = fmaxf(m.y, v.y);
        m.z = fmaxf(m.z, v.z); m.w = fmaxf(m.w, v.w);
        s.x += v.x; s.y += v.y; s.z += v.z; s.w += v.w;
    }
    const float k = 1.f / H;
    s.x *= k; s.y *= k; s.z *= k; s.w *= k;
    *(float4*)(pool2 + ((size_t)(b * 2 + 0) * C + c) * W + w0) = m;
    *(float4*)(pool2 + ((size_t)(b * 2 + 1) * C + c) * W + w0) = s;
}

// ---------------- 7x7 conv (2->1 ch) + sigmoid ----------------
__global__ __launch_bounds__(256) void conv7_sig(const float* __restrict__ pin,
                                                 const float* __restrict__ wt,
                                                 float* __restrict__ sout,
                                                 int P, int Q, int total) {
    const int n = blockIdx.x * 256 + threadIdx.x;
    if (n >= total) return;
    const int q = n % Q;
    const int t = n / Q;
    const int p = t % P;
    const int b = t / P;
    float acc = 0.f;
#pragma unroll
    for (int c2 = 0; c2 < 2; ++c2) {
#pragma unroll
        for (int i = 0; i < 7; ++i) {
            const int pp = p + i - 3;
            if (pp < 0 || pp >= P) continue;
#pragma unroll
            for (int jj = 0; jj < 7; ++jj) {
                const int qq = q + jj - 3;
                if (qq < 0 || qq >= Q) continue;
                acc += pin[((size_t)(b * 2 + c2) * P + pp) * Q + qq] * wt[c2 * 49 + i * 7 + jj];
            }
        }
    }
    sout[n] = 1.f / (1.f + expf(-acc));
}

// ---------------- out = y * (s1+s2+s3)/3, in place ----------------
__global__ __launch_bounds__(256) void final_mul(float* __restrict__ y,
                                                 const float* __restrict__ s1,
                                                 const float* __restrict__ s2,
                                                 const float* __restrict__ s3) {
    const int n   = blockIdx.x * 256 + threadIdx.x;  // per float4
    const int j   = n & 127;
    const int row = n >> 7;                          // (b*C+c)*H + h
    const int h = row & 31, c = (row >> 5) & 127, b = row >> 12;
    const int w0 = j << 2;
    float4 yv = *(float4*)(y + (size_t)row * W + w0);
    const float4 v1 = *(const float4*)(s1 + ((size_t)b * H + h) * W + w0);
    const float4 v2 = *(const float4*)(s2 + ((size_t)b * C + c) * W + w0);
    const float  g3 = s3[((size_t)b * H + h) * C + c];
    const float k = 1.f / 3.f;
    float4 o;
    o.x = yv.x * (v1.x + v2.x + g3) * k;
    o.y = yv.y * (v1.y + v2.y + g3) * k;
    o.z = yv.z * (v1.z + v2.z + g3) * k;
    o.w = yv.w * (v1.w + v2.w + g3) * k;
    *(float4*)(y + (size_t)row * W + w0) = o;
}

extern "C" void kernel_launch(void* const* d_in, const int* in_sizes, int n_in,
                              void* d_out, int out_size, void* d_ws, size_t ws_size,
                              hipStream_t stream) {
    const float* x  = (const float*)d_in[0];
    const float* wg = (const float*)d_in[1];
    const float* w1 = (const float*)d_in[2];
    const float* w2 = (const float*)d_in[3];
    const float* w3 = (const float*)d_in[4];
    float* y  = (float*)d_out;       // y lives in d_out; final multiply is in-place
    float* ws = (float*)d_ws;

    // pool1p [2,B,2,H,W] (1M floats) aliases pool2's region; it is dead before
    // pool_h writes pool2 (stream-ordered).
    float* pool1p = ws;              // [2,B,2,H,W] 1048576
    float* pool2  = ws;              // [B,2,C,W]   2097152
    float* pool1  = ws + 2097152;    // [B,2,H,W]   524288
    float* pool3  = ws + 2621440;    // [B,2,H,C]   131072
    float* s1     = ws + 2752512;    // [B,H,W]     262144
    float* s2     = ws + 3014656;    // [B,C,W]     1048576
    float* s3     = ws + 4063232;    // [B,H,C]     65536

    conv_grouped_lds<<<dim3(2, H, B), 512, 0, stream>>>(x, wg, y, pool3, pool1p);

    combine_pool1<<<dim3((B * H * W / 4) / 256), 256, 0, stream>>>(pool1p, pool1);
    pool_h<<<dim3((B * C * (W / 4)) / 256), 256, 0, stream>>>(y, pool2);

    conv7_sig<<<dim3(262144 / 256), 256, 0, stream>>>(pool1, w1, s1, H, W, 262144);
    conv7_sig<<<dim3(1048576 / 256), 256, 0, stream>>>(pool2, w2, s2, C, W, 1048576);
    conv7_sig<<<dim3(65536 / 256), 256, 0, stream>>>(pool3, w3, s3, H, C, 65536);

    final_mul<<<dim3((B * C * H * W / 4) / 256), 256, 0, stream>>>(y, s1, s2, s3);
}

// Round 5
// 237.624 us; speedup vs baseline: 1.6618x; 1.6618x over previous
//
#include <hip/hip_runtime.h>
#include <math.h>

#define B 16
#define C 128
#define H 32
#define W 512

typedef short bf16x4 __attribute__((ext_vector_type(4)));
typedef short bf16x8 __attribute__((ext_vector_type(8)));
typedef float f32x4 __attribute__((ext_vector_type(4)));

static __device__ inline unsigned short f2bf(float f) {
    unsigned u = __builtin_bit_cast(unsigned, f);
    u += 0x7fffu + ((u >> 16) & 1u);          // RNE
    return (unsigned short)(u >> 16);
}

// ---------------- prep: wg [128][64][3] f32 -> wT [2][3][64][64] bf16 ----------------
__global__ __launch_bounds__(256) void prep_wT(const float* __restrict__ wg,
                                               unsigned short* __restrict__ wT) {
    const int e = blockIdx.x * 256 + threadIdx.x;   // 24576 total
    if (e >= 24576) return;
    const int g   = e / 12288;
    const int rem = e - g * 12288;
    const int tap = rem >> 12;
    const int o   = (rem >> 6) & 63;
    const int ci  = rem & 63;
    wT[e] = f2bf(wg[((size_t)(g * 64 + o) * 64 + ci) * 3 + tap]);
}

// ---------------- Kernel A: grouped (1x3) conv via bf16 MFMA ----------------
// Block = (g, h, b), 512 threads = 8 waves = 4 o-tiles x 2 N-halves.
// x staged once to LDS as w-major bf16 tile xT[row=w+1][68ci-pad] (136 B rows).
// Weights read as A-fragments straight from global wT (L2-hot).
// Fused epilogue: pool over W (pool3, complete) + pool over C partial (pool1p).
__global__ __launch_bounds__(512, 4) void conv_mfma(
    const float* __restrict__ x, const unsigned short* __restrict__ wT,
    float* __restrict__ y, float* __restrict__ pool3, float* __restrict__ pool1p) {
    __shared__ __align__(16) char xsb[514 * 136];   // 69,904 B

    const int g = blockIdx.x;
    const int h = blockIdx.y;
    const int b = blockIdx.z;
    const int t = threadIdx.x;
    const int lane = t & 63;
    const int col  = lane & 15;          // N sub-index (w) / M sub for A
    const int q    = lane >> 4;          // k-group
    const int wave = t >> 6;             // 0..7
    const int ot   = wave >> 1;          // o-tile 0..3
    const int nh   = wave & 1;           // N half 0..1

    // ---- A-fragments from global wT (6 x 16B per lane) ----
    const unsigned short* wA =
        wT + (size_t)g * 12288 + ot * 1024 + col * 64 + q * 8;
    bf16x8 afr[3][2];
#pragma unroll
    for (int tap = 0; tap < 3; ++tap)
#pragma unroll
        for (int kk = 0; kk < 2; ++kk)
            afr[tap][kk] = *(const bf16x8*)(wA + tap * 4096 + kk * 32);

    // ---- zero halo rows (w = -1 and w = 512) ----
    if (t < 68) {
        const int row = (t < 34) ? 0 : 513;
        const int dw  = (t < 34) ? t : (t - 34);
        ((float*)(xsb + row * 136))[dw] = 0.f;
    }

    // ---- stage x -> xT[w+1][ci] bf16, transposing 4ci x 4w micro-tiles ----
    const int w0 = (t & 127) * 4;
    const int ct = t >> 7;                           // 0..3
#pragma unroll
    for (int p = 0; p < 4; ++p) {
        const int ci0 = p * 16 + ct * 4;
        float a[4][4];
#pragma unroll
        for (int i = 0; i < 4; ++i) {
            const float4 v =
                *(const float4*)(x + ((size_t)(b * C + g * 64 + ci0 + i) * H + h) * W + w0);
            a[i][0] = v.x; a[i][1] = v.y; a[i][2] = v.z; a[i][3] = v.w;
        }
#pragma unroll
        for (int j = 0; j < 4; ++j) {
            const int jj = (j + (t & 3)) & 3;        // stagger to spread banks
            bf16x4 pk;
            pk[0] = (short)f2bf(a[0][jj]); pk[1] = (short)f2bf(a[1][jj]);
            pk[2] = (short)f2bf(a[2][jj]); pk[3] = (short)f2bf(a[3][jj]);
            *(bf16x4*)(xsb + (size_t)(w0 + jj + 1) * 136 + ci0 * 2) = pk;
        }
    }
    __syncthreads();

    // ---- MFMA main loop: this wave: o-tile ot, w-tiles nh*16 .. nh*16+15 ----
    f32x4 acc[16];
#pragma unroll
    for (int i = 0; i < 16; ++i) acc[i] = (f32x4){0.f, 0.f, 0.f, 0.f};

    const char* bbase = xsb + col * 136 + q * 16 + nh * (256 * 136);
#pragma unroll
    for (int wt = 0; wt < 16; ++wt) {
#pragma unroll
        for (int kk = 0; kk < 2; ++kk) {
#pragma unroll
            for (int tap = 0; tap < 3; ++tap) {
                const int off = (wt * 16 + tap) * 136 + kk * 64;
                const bf16x4 lo = *(const bf16x4*)(bbase + off);
                const bf16x4 hi = *(const bf16x4*)(bbase + off + 8);
                const bf16x8 bfr = __builtin_shufflevector(lo, hi, 0, 1, 2, 3, 4, 5, 6, 7);
                acc[wt] = __builtin_amdgcn_mfma_f32_16x16x32_bf16(
                    afr[tap][kk], bfr, acc[wt], 0, 0, 0);
            }
        }
    }

    // ---- store y: lane holds o = ot*16 + q*4 + r, w = nh*256 + wt*16 + col ----
    {
        float* yb = y + ((size_t)(b * C + g * 64 + ot * 16 + q * 4) * H + h) * W +
                    nh * 256 + col;
#pragma unroll
        for (int r = 0; r < 4; ++r)
#pragma unroll
            for (int wt = 0; wt < 16; ++wt)
                yb[(size_t)r * H * W + wt * 16] = acc[wt][r];
    }

    __syncthreads();                       // all waves done reading xsb
    float* pcm = (float*)xsb;              // [4][512]
    float* pcs = pcm + 2048;               // [4][512]
    float* pwb = pcs + 2048;               // [4][2][4][4][2] = 256 floats

    // ---- pool over W: per (o) max/sum across this wave's 256 w ----
    {
        float wm[4], wsv[4];
#pragma unroll
        for (int r = 0; r < 4; ++r) { wm[r] = acc[0][r]; wsv[r] = acc[0][r]; }
#pragma unroll
        for (int wt = 1; wt < 16; ++wt)
#pragma unroll
            for (int r = 0; r < 4; ++r) {
                wm[r]  = fmaxf(wm[r], acc[wt][r]);
                wsv[r] += acc[wt][r];
            }
#pragma unroll
        for (int off = 8; off; off >>= 1)
#pragma unroll
            for (int r = 0; r < 4; ++r) {
                wm[r]  = fmaxf(wm[r], __shfl_xor(wm[r], off));
                wsv[r] += __shfl_xor(wsv[r], off);
            }
        if (col == 0)
#pragma unroll
            for (int r = 0; r < 4; ++r) {
                const int idx = (((ot * 2 + nh) * 4 + q) * 4 + r) * 2;
                pwb[idx]     = wm[r];
                pwb[idx + 1] = wsv[r];
            }
    }
    // ---- pool over C partial: reduce over this wave's 16 o per w ----
    {
        float cm[16], cs[16];
#pragma unroll
        for (int wt = 0; wt < 16; ++wt) {
            cm[wt] = fmaxf(fmaxf(acc[wt][0], acc[wt][1]), fmaxf(acc[wt][2], acc[wt][3]));
            cs[wt] = acc[wt][0] + acc[wt][1] + acc[wt][2] + acc[wt][3];
        }
#pragma unroll
        for (int off = 16; off <= 32; off <<= 1)
#pragma unroll
            for (int wt = 0; wt < 16; ++wt) {
                cm[wt] = fmaxf(cm[wt], __shfl_xor(cm[wt], off));
                cs[wt] += __shfl_xor(cs[wt], off);
            }
        if (q == 0)
#pragma unroll
            for (int wt = 0; wt < 16; ++wt) {
                pcm[ot * 512 + nh * 256 + wt * 16 + col] = cm[wt];
                pcs[ot * 512 + nh * 256 + wt * 16 + col] = cs[wt];
            }
    }
    __syncthreads();

    if (t < 64) {                          // pool3 write (complete over W)
        const int o2 = t >> 4, q2 = (t >> 2) & 3, r2 = t & 3;
        const int i0 = (((o2 * 2 + 0) * 4 + q2) * 4 + r2) * 2;
        const int i1 = (((o2 * 2 + 1) * 4 + q2) * 4 + r2) * 2;
        const float m0 = fmaxf(pwb[i0], pwb[i1]);
        const float s0 = (pwb[i0 + 1] + pwb[i1 + 1]) * (1.f / W);
        const int c = g * 64 + o2 * 16 + q2 * 4 + r2;
        pool3[((size_t)(b * 2 + 0) * H + h) * C + c] = m0;
        pool3[((size_t)(b * 2 + 1) * H + h) * C + c] = s0;
    }
    {                                      // pool1p partial (this group's 64 ch)
        const int w = t;
        float m0 = -INFINITY, s0 = 0.f;
#pragma unroll
        for (int o2 = 0; o2 < 4; ++o2) {
            m0 = fmaxf(m0, pcm[o2 * 512 + w]);
            s0 += pcs[o2 * 512 + w];
        }
        pool1p[((size_t)(g * B + b) * 2 + 0) * (H * W) + h * W + w] = m0;
        pool1p[((size_t)(g * B + b) * 2 + 1) * (H * W) + h * W + w] = s0;
    }
}

// ---------------- combine pool1 partials (2 groups) -> pool1 [B,2,H,W] ----------------
__global__ __launch_bounds__(256) void combine_pool1(const float* __restrict__ p1p,
                                                     float* __restrict__ pool1) {
    const int n = blockIdx.x * 256 + threadIdx.x;   // over B*H*W/4
    const int b = n >> 12;
    const int o = (n & 4095) * 4;                   // h*W+w offset
    const float4 m0 = *(const float4*)(p1p + ((size_t)(0 * B + b) * 2 + 0) * (H * W) + o);
    const float4 m1 = *(const float4*)(p1p + ((size_t)(1 * B + b) * 2 + 0) * (H * W) + o);
    const float4 s0 = *(const float4*)(p1p + ((size_t)(0 * B + b) * 2 + 1) * (H * W) + o);
    const float4 s1 = *(const float4*)(p1p + ((size_t)(1 * B + b) * 2 + 1) * (H * W) + o);
    float4 mo, so;
    mo.x = fmaxf(m0.x, m1.x); mo.y = fmaxf(m0.y, m1.y);
    mo.z = fmaxf(m0.z, m1.z); mo.w = fmaxf(m0.w, m1.w);
    const float k = 1.f / C;
    so.x = (s0.x + s1.x) * k; so.y = (s0.y + s1.y) * k;
    so.z = (s0.z + s1.z) * k; so.w = (s0.w + s1.w) * k;
    *(float4*)(pool1 + ((size_t)(b * 2 + 0) * H * W) + o) = mo;
    *(float4*)(pool1 + ((size_t)(b * 2 + 1) * H * W) + o) = so;
}

// ---------------- pool over H -> [B,2,C,W], float4 ----------------
__global__ __launch_bounds__(256) void pool_h(const float* __restrict__ y,
                                              float* __restrict__ pool2) {
    const int n  = blockIdx.x * 256 + threadIdx.x;  // over B*C*(W/4)
    const int b  = n >> 14;
    const int c  = (n >> 7) & 127;
    const int w0 = (n & 127) << 2;
    const float* p = y + ((size_t)(b * C + c) * H) * W + w0;
    float4 m = *(const float4*)p;
    float4 s = m;
    for (int hh = 1; hh < H; ++hh) {
        const float4 v = *(const float4*)(p + (size_t)hh * W);
        m.x = fmaxf(m.x, v.x); m.y = fmaxf(m.y, v.y);
        m.z = fmaxf(m.z, v.z); m.w = fmaxf(m.w, v.w);
        s.x += v.x; s.y += v.y; s.z += v.z; s.w += v.w;
    }
    const float k = 1.f / H;
    s.x *= k; s.y *= k; s.z *= k; s.w *= k;
    *(float4*)(pool2 + ((size_t)(b * 2 + 0) * C + c) * W + w0) = m;
    *(float4*)(pool2 + ((size_t)(b * 2 + 1) * C + c) * W + w0) = s;
}

// ---------------- 7x7 conv (2->1 ch) + sigmoid ----------------
__global__ __launch_bounds__(256) void conv7_sig(const float* __restrict__ pin,
                                                 const float* __restrict__ wt,
                                                 float* __restrict__ sout,
                                                 int P, int Q, int total) {
    const int n = blockIdx.x * 256 + threadIdx.x;
    if (n >= total) return;
    const int q = n % Q;
    const int t = n / Q;
    const int p = t % P;
    const int b = t / P;
    float acc = 0.f;
#pragma unroll
    for (int c2 = 0; c2 < 2; ++c2) {
#pragma unroll
        for (int i = 0; i < 7; ++i) {
            const int pp = p + i - 3;
            if (pp < 0 || pp >= P) continue;
#pragma unroll
            for (int jj = 0; jj < 7; ++jj) {
                const int qq = q + jj - 3;
                if (qq < 0 || qq >= Q) continue;
                acc += pin[((size_t)(b * 2 + c2) * P + pp) * Q + qq] * wt[c2 * 49 + i * 7 + jj];
            }
        }
    }
    sout[n] = 1.f / (1.f + expf(-acc));
}

// ---------------- out = y * (s1+s2+s3)/3, in place ----------------
__global__ __launch_bounds__(256) void final_mul(float* __restrict__ y,
                                                 const float* __restrict__ s1,
                                                 const float* __restrict__ s2,
                                                 const float* __restrict__ s3) {
    const int n   = blockIdx.x * 256 + threadIdx.x;  // per float4
    const int j   = n & 127;
    const int row = n >> 7;                          // (b*C+c)*H + h
    const int h = row & 31, c = (row >> 5) & 127, b = row >> 12;
    const int w0 = j << 2;
    float4 yv = *(float4*)(y + (size_t)row * W + w0);
    const float4 v1 = *(const float4*)(s1 + ((size_t)b * H + h) * W + w0);
    const float4 v2 = *(const float4*)(s2 + ((size_t)b * C + c) * W + w0);
    const float  g3 = s3[((size_t)b * H + h) * C + c];
    const float k = 1.f / 3.f;
    float4 o;
    o.x = yv.x * (v1.x + v2.x + g3) * k;
    o.y = yv.y * (v1.y + v2.y + g3) * k;
    o.z = yv.z * (v1.z + v2.z + g3) * k;
    o.w = yv.w * (v1.w + v2.w + g3) * k;
    *(float4*)(y + (size_t)row * W + w0) = o;
}

extern "C" void kernel_launch(void* const* d_in, const int* in_sizes, int n_in,
                              void* d_out, int out_size, void* d_ws, size_t ws_size,
                              hipStream_t stream) {
    const float* x  = (const float*)d_in[0];
    const float* wg = (const float*)d_in[1];
    const float* w1 = (const float*)d_in[2];
    const float* w2 = (const float*)d_in[3];
    const float* w3 = (const float*)d_in[4];
    float* y  = (float*)d_out;       // y lives in d_out; final multiply is in-place
    float* ws = (float*)d_ws;

    // Workspace layout (floats). pool1p and wT live inside pool2's region,
    // which is only written later by pool_h (stream-ordered, so safe).
    float* pool1p = ws;                               // [2,B,2,H,W] 1048576
    unsigned short* wT = (unsigned short*)(ws + 1048576);  // 12288 f32 slots
    float* pool2  = ws;                               // [B,2,C,W]   2097152
    float* pool1  = ws + 2097152;                     // [B,2,H,W]   524288
    float* pool3  = ws + 2621440;                     // [B,2,H,C]   131072
    float* s1     = ws + 2752512;                     // [B,H,W]     262144
    float* s2     = ws + 3014656;                     // [B,C,W]     1048576
    float* s3     = ws + 4063232;                     // [B,H,C]     65536

    prep_wT<<<dim3(96), 256, 0, stream>>>(wg, wT);
    conv_mfma<<<dim3(2, H, B), 512, 0, stream>>>(x, wT, y, pool3, pool1p);

    combine_pool1<<<dim3((B * H * W / 4) / 256), 256, 0, stream>>>(pool1p, pool1);
    pool_h<<<dim3((B * C * (W / 4)) / 256), 256, 0, stream>>>(y, pool2);

    conv7_sig<<<dim3(262144 / 256), 256, 0, stream>>>(pool1, w1, s1, H, W, 262144);
    conv7_sig<<<dim3(1048576 / 256), 256, 0, stream>>>(pool2, w2, s2, C, W, 1048576);
    conv7_sig<<<dim3(65536 / 256), 256, 0, stream>>>(pool3, w3, s3, H, C, 65536);

    final_mul<<<dim3((B * C * H * W / 4) / 256), 256, 0, stream>>>(y, s1, s2, s3);
}

// Round 6
// 224.964 us; speedup vs baseline: 1.7553x; 1.0563x over previous
//
#include <hip/hip_runtime.h>
#include <math.h>

#define B 16
#define C 128
#define H 32
#define W 512

typedef short bf16x4 __attribute__((ext_vector_type(4)));
typedef short bf16x8 __attribute__((ext_vector_type(8)));
typedef float f32x4 __attribute__((ext_vector_type(4)));

static __device__ inline unsigned short f2bf(float f) {
    unsigned u = __builtin_bit_cast(unsigned, f);
    u += 0x7fffu + ((u >> 16) & 1u);          // RNE
    return (unsigned short)(u >> 16);
}

// ---------------- prep: wg [128][64][3] f32 -> wT [2][3][64][64] bf16 ----------------
__global__ __launch_bounds__(256) void prep_wT(const float* __restrict__ wg,
                                               unsigned short* __restrict__ wT) {
    const int e = blockIdx.x * 256 + threadIdx.x;   // 24576 total
    if (e >= 24576) return;
    const int g   = e / 12288;
    const int rem = e - g * 12288;
    const int tap = rem >> 12;
    const int o   = (rem >> 6) & 63;
    const int ci  = rem & 63;
    wT[e] = f2bf(wg[((size_t)(g * 64 + o) * 64 + ci) * 3 + tap]);
}

// ---------------- Kernel A: grouped (1x3) conv via bf16 MFMA, w-split ----------------
// Block = (g, wq, h, b): 64 o x 128 w. 256 threads = 4 waves = 4 o-tiles.
// x slice staged to LDS w-major bf16 [row = local_w+1][64 ci] (136 B rows, 130 rows).
// Fused epilogue: pool over W partial (pool3p, 4-way) + pool over C partial (pool1p).
__global__ __launch_bounds__(256, 6) void conv_mfma(
    const float* __restrict__ x, const unsigned short* __restrict__ wT,
    float* __restrict__ y, float* __restrict__ pool3p, float* __restrict__ pool1p) {
    __shared__ __align__(16) char xsb[130 * 136];   // 17,680 B

    const int bx = blockIdx.x;          // g*4 + wq
    const int g  = bx >> 2;
    const int wq = bx & 3;
    const int h = blockIdx.y;
    const int b = blockIdx.z;
    const int t = threadIdx.x;
    const int lane = t & 63;
    const int col  = lane & 15;
    const int q    = lane >> 4;
    const int wave = t >> 6;            // o-tile 0..3

    // ---- stage x -> xT[local_w+1][ci] bf16 ----
    const int w0  = (t & 31) * 4;       // local w start
    const int cig = t >> 5;             // ci group 0..7 (8 ci each)
    {
        float a[8][4];
        const float* xb =
            x + ((size_t)(b * C + g * 64 + cig * 8) * H + h) * W + wq * 128 + w0;
#pragma unroll
        for (int i = 0; i < 8; ++i) {
            const float4 v = *(const float4*)(xb + (size_t)i * H * W);
            a[i][0] = v.x; a[i][1] = v.y; a[i][2] = v.z; a[i][3] = v.w;
        }
#pragma unroll
        for (int j = 0; j < 4; ++j) {
            unsigned p0, p1, p2, p3;
            asm("v_cvt_pk_bf16_f32 %0, %1, %2" : "=v"(p0) : "v"(a[0][j]), "v"(a[1][j]));
            asm("v_cvt_pk_bf16_f32 %0, %1, %2" : "=v"(p1) : "v"(a[2][j]), "v"(a[3][j]));
            asm("v_cvt_pk_bf16_f32 %0, %1, %2" : "=v"(p2) : "v"(a[4][j]), "v"(a[5][j]));
            asm("v_cvt_pk_bf16_f32 %0, %1, %2" : "=v"(p3) : "v"(a[6][j]), "v"(a[7][j]));
            uint4 pk; pk.x = p0; pk.y = p1; pk.z = p2; pk.w = p3;
            *(uint4*)(xsb + (size_t)(w0 + j + 1) * 136 + cig * 16) = pk;
        }
    }
    // ---- halo rows 0 (w-1) and 129 (w+128) ----
    if (t < 128) {
        const int side = t >> 6;        // 0 = left, 1 = right
        const int ci   = t & 63;
        const int row  = side ? 129 : 0;
        const int gw   = wq * 128 + (side ? 128 : -1);
        float v = 0.f;
        if ((side == 0 && wq > 0) || (side == 1 && wq < 3))
            v = x[((size_t)(b * C + g * 64 + ci) * H + h) * W + gw];
        *(unsigned short*)(xsb + (size_t)row * 136 + ci * 2) = f2bf(v);
    }

    // ---- A-fragments from global wT (L2-hot), issued before barrier ----
    const unsigned short* wA =
        wT + (size_t)g * 12288 + wave * 1024 + col * 64 + q * 8;
    bf16x8 afr[3][2];
#pragma unroll
    for (int tap = 0; tap < 3; ++tap)
#pragma unroll
        for (int kk = 0; kk < 2; ++kk)
            afr[tap][kk] = *(const bf16x8*)(wA + tap * 4096 + kk * 32);

    __syncthreads();

    // ---- MFMA: this wave: o-tile `wave`, 8 w-tiles of 16 ----
    f32x4 acc[8];
#pragma unroll
    for (int i = 0; i < 8; ++i) acc[i] = (f32x4){0.f, 0.f, 0.f, 0.f};

    const char* bbase = xsb + col * 136 + q * 16;
#pragma unroll
    for (int wt = 0; wt < 8; ++wt) {
#pragma unroll
        for (int kk = 0; kk < 2; ++kk) {
#pragma unroll
            for (int tap = 0; tap < 3; ++tap) {
                const int off = (wt * 16 + tap) * 136 + kk * 64;
                const bf16x4 lo = *(const bf16x4*)(bbase + off);
                const bf16x4 hi = *(const bf16x4*)(bbase + off + 8);
                const bf16x8 bfr = __builtin_shufflevector(lo, hi, 0, 1, 2, 3, 4, 5, 6, 7);
                acc[wt] = __builtin_amdgcn_mfma_f32_16x16x32_bf16(
                    afr[tap][kk], bfr, acc[wt], 0, 0, 0);
            }
        }
    }

    // ---- store y: o = g*64 + wave*16 + q*4 + r, w = wq*128 + wt*16 + col ----
    {
        float* yb = y + ((size_t)(b * C + g * 64 + wave * 16 + q * 4) * H + h) * W +
                    wq * 128 + col;
#pragma unroll
        for (int r = 0; r < 4; ++r)
#pragma unroll
            for (int wt = 0; wt < 8; ++wt)
                yb[(size_t)r * H * W + wt * 16] = acc[wt][r];
    }

    __syncthreads();                     // xsb free; reuse for reductions
    float* pcm = (float*)xsb;            // [4][128]
    float* pcs = pcm + 512;              // [4][128]
    float* pwb = pcs + 512;              // [4][4][4][2] = 128 floats

    // ---- pool over this block's 128 w, per o ----
    {
        float wm[4], wsv[4];
#pragma unroll
        for (int r = 0; r < 4; ++r) { wm[r] = acc[0][r]; wsv[r] = acc[0][r]; }
#pragma unroll
        for (int wt = 1; wt < 8; ++wt)
#pragma unroll
            for (int r = 0; r < 4; ++r) {
                wm[r]  = fmaxf(wm[r], acc[wt][r]);
                wsv[r] += acc[wt][r];
            }
#pragma unroll
        for (int off = 8; off; off >>= 1)
#pragma unroll
            for (int r = 0; r < 4; ++r) {
                wm[r]  = fmaxf(wm[r], __shfl_xor(wm[r], off));
                wsv[r] += __shfl_xor(wsv[r], off);
            }
        if (col == 0)
#pragma unroll
            for (int r = 0; r < 4; ++r) {
                const int idx = ((wave * 4 + q) * 4 + r) * 2;
                pwb[idx]     = wm[r];
                pwb[idx + 1] = wsv[r];
            }
    }
    // ---- pool over this wave's 16 o, per w ----
    {
        float cm[8], cs[8];
#pragma unroll
        for (int wt = 0; wt < 8; ++wt) {
            cm[wt] = fmaxf(fmaxf(acc[wt][0], acc[wt][1]), fmaxf(acc[wt][2], acc[wt][3]));
            cs[wt] = acc[wt][0] + acc[wt][1] + acc[wt][2] + acc[wt][3];
        }
#pragma unroll
        for (int off = 16; off <= 32; off <<= 1)
#pragma unroll
            for (int wt = 0; wt < 8; ++wt) {
                cm[wt] = fmaxf(cm[wt], __shfl_xor(cm[wt], off));
                cs[wt] += __shfl_xor(cs[wt], off);
            }
        if (lane < 16)
#pragma unroll
            for (int wt = 0; wt < 8; ++wt) {
                pcm[wave * 128 + wt * 16 + col] = cm[wt];
                pcs[wave * 128 + wt * 16 + col] = cs[wt];
            }
    }
    __syncthreads();

    if (t < 64) {                        // pool3 partial: c = g*64 + t (raw m, raw sum)
        const float m0 = pwb[t * 2 + 0];
        const float s0 = pwb[t * 2 + 1];
        const int c = g * 64 + t;        // t = ((wave*4+q)*4+r) = o within group
        pool3p[(((size_t)wq * B + b) * 2 + 0) * (H * C) + h * C + c] = m0;
        pool3p[(((size_t)wq * B + b) * 2 + 1) * (H * C) + h * C + c] = s0;
    }
    if (t < 128) {                       // pool1 partial for w = wq*128 + t
        float m0 = pcm[t], s0 = pcs[t];
#pragma unroll
        for (int ot = 1; ot < 4; ++ot) {
            m0 = fmaxf(m0, pcm[ot * 128 + t]);
            s0 += pcs[ot * 128 + t];
        }
        pool1p[((size_t)(g * B + b) * 2 + 0) * (H * W) + h * W + wq * 128 + t] = m0;
        pool1p[((size_t)(g * B + b) * 2 + 1) * (H * W) + h * W + wq * 128 + t] = s0;
    }
}

// ---------------- combine pool1 partials (2 groups) -> pool1 [B,2,H,W] ----------------
__global__ __launch_bounds__(256) void combine_pool1(const float* __restrict__ p1p,
                                                     float* __restrict__ pool1) {
    const int n = blockIdx.x * 256 + threadIdx.x;   // over B*H*W/4
    const int b = n >> 12;
    const int o = (n & 4095) * 4;                   // h*W+w offset
    const float4 m0 = *(const float4*)(p1p + ((size_t)(0 * B + b) * 2 + 0) * (H * W) + o);
    const float4 m1 = *(const float4*)(p1p + ((size_t)(1 * B + b) * 2 + 0) * (H * W) + o);
    const float4 s0 = *(const float4*)(p1p + ((size_t)(0 * B + b) * 2 + 1) * (H * W) + o);
    const float4 s1 = *(const float4*)(p1p + ((size_t)(1 * B + b) * 2 + 1) * (H * W) + o);
    float4 mo, so;
    mo.x = fmaxf(m0.x, m1.x); mo.y = fmaxf(m0.y, m1.y);
    mo.z = fmaxf(m0.z, m1.z); mo.w = fmaxf(m0.w, m1.w);
    const float k = 1.f / C;
    so.x = (s0.x + s1.x) * k; so.y = (s0.y + s1.y) * k;
    so.z = (s0.z + s1.z) * k; so.w = (s0.w + s1.w) * k;
    *(float4*)(pool1 + ((size_t)(b * 2 + 0) * H * W) + o) = mo;
    *(float4*)(pool1 + ((size_t)(b * 2 + 1) * H * W) + o) = so;
}

// ---------------- combine pool3 partials (4 wq) -> pool3 [B,2,H,C] ----------------
__global__ __launch_bounds__(256) void combine_pool3(const float* __restrict__ p3p,
                                                     float* __restrict__ pool3) {
    const int n = blockIdx.x * 256 + threadIdx.x;   // over B*H*C = 65536
    const int b = n >> 12;
    const int o = n & 4095;                          // h*C + c
    float m = -INFINITY, s = 0.f;
#pragma unroll
    for (int wq = 0; wq < 4; ++wq) {
        m = fmaxf(m, p3p[(((size_t)wq * B + b) * 2 + 0) * (H * C) + o]);
        s += p3p[(((size_t)wq * B + b) * 2 + 1) * (H * C) + o];
    }
    pool3[((size_t)(b * 2 + 0) * H * C) + o] = m;
    pool3[((size_t)(b * 2 + 1) * H * C) + o] = s * (1.f / W);
}

// ---------------- pool over H -> [B,2,C,W], float4 ----------------
__global__ __launch_bounds__(256) void pool_h(const float* __restrict__ y,
                                              float* __restrict__ pool2) {
    const int n  = blockIdx.x * 256 + threadIdx.x;  // over B*C*(W/4)
    const int b  = n >> 14;
    const int c  = (n >> 7) & 127;
    const int w0 = (n & 127) << 2;
    const float* p = y + ((size_t)(b * C + c) * H) * W + w0;
    float4 m = *(const float4*)p;
    float4 s = m;
    for (int hh = 1; hh < H; ++hh) {
        const float4 v = *(const float4*)(p + (size_t)hh * W);
        m.x = fmaxf(m.x, v.x); m.y = fmaxf(m.y, v.y);
        m.z = fmaxf(m.z, v.z); m.w = fmaxf(m.w, v.w);
        s.x += v.x; s.y += v.y; s.z += v.z; s.w += v.w;
    }
    const float k = 1.f / H;
    s.x *= k; s.y *= k; s.z *= k; s.w *= k;
    *(float4*)(pool2 + ((size_t)(b * 2 + 0) * C + c) * W + w0) = m;
    *(float4*)(pool2 + ((size_t)(b * 2 + 1) * C + c) * W + w0) = s;
}

// ---------------- 7x7 conv (2->1 ch) + sigmoid ----------------
__global__ __launch_bounds__(256) void conv7_sig(const float* __restrict__ pin,
                                                 const float* __restrict__ wt,
                                                 float* __restrict__ sout,
                                                 int P, int Q, int total) {
    const int n = blockIdx.x * 256 + threadIdx.x;
    if (n >= total) return;
    const int q = n % Q;
    const int t = n / Q;
    const int p = t % P;
    const int b = t / P;
    float acc = 0.f;
#pragma unroll
    for (int c2 = 0; c2 < 2; ++c2) {
#pragma unroll
        for (int i = 0; i < 7; ++i) {
            const int pp = p + i - 3;
            if (pp < 0 || pp >= P) continue;
#pragma unroll
            for (int jj = 0; jj < 7; ++jj) {
                const int qq = q + jj - 3;
                if (qq < 0 || qq >= Q) continue;
                acc += pin[((size_t)(b * 2 + c2) * P + pp) * Q + qq] * wt[c2 * 49 + i * 7 + jj];
            }
        }
    }
    sout[n] = 1.f / (1.f + expf(-acc));
}

// ---------------- out = y * (s1+s2+s3)/3, in place ----------------
__global__ __launch_bounds__(256) void final_mul(float* __restrict__ y,
                                                 const float* __restrict__ s1,
                                                 const float* __restrict__ s2,
                                                 const float* __restrict__ s3) {
    const int n   = blockIdx.x * 256 + threadIdx.x;  // per float4
    const int j   = n & 127;
    const int row = n >> 7;                          // (b*C+c)*H + h
    const int h = row & 31, c = (row >> 5) & 127, b = row >> 12;
    const int w0 = j << 2;
    float4 yv = *(float4*)(y + (size_t)row * W + w0);
    const float4 v1 = *(const float4*)(s1 + ((size_t)b * H + h) * W + w0);
    const float4 v2 = *(const float4*)(s2 + ((size_t)b * C + c) * W + w0);
    const float  g3 = s3[((size_t)b * H + h) * C + c];
    const float k = 1.f / 3.f;
    float4 o;
    o.x = yv.x * (v1.x + v2.x + g3) * k;
    o.y = yv.y * (v1.y + v2.y + g3) * k;
    o.z = yv.z * (v1.z + v2.z + g3) * k;
    o.w = yv.w * (v1.w + v2.w + g3) * k;
    *(float4*)(y + (size_t)row * W + w0) = o;
}

extern "C" void kernel_launch(void* const* d_in, const int* in_sizes, int n_in,
                              void* d_out, int out_size, void* d_ws, size_t ws_size,
                              hipStream_t stream) {
    const float* x  = (const float*)d_in[0];
    const float* wg = (const float*)d_in[1];
    const float* w1 = (const float*)d_in[2];
    const float* w2 = (const float*)d_in[3];
    const float* w3 = (const float*)d_in[4];
    float* y  = (float*)d_out;       // y lives in d_out; final multiply is in-place
    float* ws = (float*)d_ws;

    // Workspace (floats). pool1p/pool3p/wT live inside pool2's region; they are
    // all dead before pool_h writes pool2 (stream-ordered).
    float* pool1p = ws;                                    // [2,B,2,H,W]  1,048,576
    float* pool3p = ws + 1048576;                          // [4,B,2,H,C]    524,288
    unsigned short* wT = (unsigned short*)(ws + 1572864);  // 24,576 bf16
    float* pool2  = ws;                                    // [B,2,C,W]    2,097,152
    float* pool1  = ws + 2097152;                          // [B,2,H,W]      524,288
    float* pool3  = ws + 2621440;                          // [B,2,H,C]      131,072
    float* s1     = ws + 2752512;                          // [B,H,W]        262,144
    float* s2     = ws + 3014656;                          // [B,C,W]      1,048,576
    float* s3     = ws + 4063232;                          // [B,H,C]         65,536

    prep_wT<<<dim3(96), 256, 0, stream>>>(wg, wT);
    conv_mfma<<<dim3(8, H, B), 256, 0, stream>>>(x, wT, y, pool3p, pool1p);

    combine_pool1<<<dim3((B * H * W / 4) / 256), 256, 0, stream>>>(pool1p, pool1);
    combine_pool3<<<dim3((B * H * C) / 256), 256, 0, stream>>>(pool3p, pool3);
    pool_h<<<dim3((B * C * (W / 4)) / 256), 256, 0, stream>>>(y, pool2);

    conv7_sig<<<dim3(262144 / 256), 256, 0, stream>>>(pool1, w1, s1, H, W, 262144);
    conv7_sig<<<dim3(1048576 / 256), 256, 0, stream>>>(pool2, w2, s2, C, W, 1048576);
    conv7_sig<<<dim3(65536 / 256), 256, 0, stream>>>(pool3, w3, s3, H, C, 65536);

    final_mul<<<dim3((B * C * H * W / 4) / 256), 256, 0, stream>>>(y, s1, s2, s3);
}

// Round 7
// 203.188 us; speedup vs baseline: 1.9435x; 1.1072x over previous
//
#include <hip/hip_runtime.h>
#include <math.h>

#define B 16
#define C 128
#define H 32
#define W 512

typedef short bf16x4 __attribute__((ext_vector_type(4)));
typedef short bf16x8 __attribute__((ext_vector_type(8)));
typedef float f32x4 __attribute__((ext_vector_type(4)));

static __device__ inline unsigned short f2bf(float f) {
    unsigned u = __builtin_bit_cast(unsigned, f);
    u += 0x7fffu + ((u >> 16) & 1u);          // RNE
    return (unsigned short)(u >> 16);
}

// ---------------- prep: wg [128][64][3] f32 -> wT [2][3][64][64] bf16 ----------------
__global__ __launch_bounds__(256) void prep_wT(const float* __restrict__ wg,
                                               unsigned short* __restrict__ wT) {
    const int e = blockIdx.x * 256 + threadIdx.x;   // 24576 total
    if (e >= 24576) return;
    const int g   = e / 12288;
    const int rem = e - g * 12288;
    const int tap = rem >> 12;
    const int o   = (rem >> 6) & 63;
    const int ci  = rem & 63;
    wT[e] = f2bf(wg[((size_t)(g * 64 + o) * 64 + ci) * 3 + tap]);
}

// ---------------- Kernel A: grouped (1x3) conv via bf16 MFMA, pipelined over h ----
// Block = (g, wq, hq, b): 64 o x 128 w x 4 h. 256 threads = 4 waves = 4 o-tiles.
// Double-buffered LDS x tile [130 rows][136 B]; reg-staged loads issued 2 h ahead.
__global__ __launch_bounds__(256, 4) void conv_mfma(
    const float* __restrict__ x, const unsigned short* __restrict__ wT,
    float* __restrict__ y, float* __restrict__ pool3p, float* __restrict__ pool1p) {
    __shared__ __align__(16) char xsb[2][130 * 136];  // 35,360 B
    __shared__ float pcm[4 * 128];                    // 2 KB
    __shared__ float pcs[4 * 128];                    // 2 KB

    const int bx = blockIdx.x;          // g*4 + wq
    const int g  = bx >> 2;
    const int wq = bx & 3;
    const int hq = blockIdx.y;          // 0..7 (4 h each)
    const int b  = blockIdx.z;
    const int t  = threadIdx.x;
    const int lane = t & 63;
    const int col  = lane & 15;
    const int q    = lane >> 4;
    const int wave = t >> 6;            // o-tile 0..3

    // ---- weight A-fragments, loaded once per block (L2-hot) ----
    const unsigned short* wA =
        wT + (size_t)g * 12288 + wave * 1024 + col * 64 + q * 8;
    bf16x8 afr[3][2];
#pragma unroll
    for (int tap = 0; tap < 3; ++tap)
#pragma unroll
        for (int kk = 0; kk < 2; ++kk)
            afr[tap][kk] = *(const bf16x8*)(wA + tap * 4096 + kk * 32);

    // ---- staging state ----
    float a[8][4];
    float hv = 0.f;
    const int w0  = (t & 31) * 4;       // local w start
    const int cig = t >> 5;             // ci group 0..7
    const float* xb0 = x + (size_t)(b * C + g * 64 + cig * 8) * (H * W) + wq * 128 + w0;
    const int side = (t >> 6) & 1;      // halo side (valid t<128)
    const int hci  = t & 63;
    const int gw   = wq * 128 + (side ? 128 : -1);
    const bool hvalid = (t < 128) && ((side == 0) ? (wq > 0) : (wq < 3));
    const float* xh0 = x + (size_t)(b * C + g * 64 + hci) * (H * W) + gw;

    auto LOADX = [&](int h) {
#pragma unroll
        for (int i = 0; i < 8; ++i) {
            const float4 v = *(const float4*)(xb0 + (size_t)i * (H * W) + h * W);
            a[i][0] = v.x; a[i][1] = v.y; a[i][2] = v.z; a[i][3] = v.w;
        }
        hv = hvalid ? xh0[h * W] : 0.f;
    };
    auto WRITEX = [&](char* buf) {
#pragma unroll
        for (int j = 0; j < 4; ++j) {
            unsigned p0, p1, p2, p3;
            asm("v_cvt_pk_bf16_f32 %0, %1, %2" : "=v"(p0) : "v"(a[0][j]), "v"(a[1][j]));
            asm("v_cvt_pk_bf16_f32 %0, %1, %2" : "=v"(p1) : "v"(a[2][j]), "v"(a[3][j]));
            asm("v_cvt_pk_bf16_f32 %0, %1, %2" : "=v"(p2) : "v"(a[4][j]), "v"(a[5][j]));
            asm("v_cvt_pk_bf16_f32 %0, %1, %2" : "=v"(p3) : "v"(a[6][j]), "v"(a[7][j]));
            uint4 pk; pk.x = p0; pk.y = p1; pk.z = p2; pk.w = p3;
            *(uint4*)(buf + (size_t)(w0 + j + 1) * 136 + cig * 16) = pk;
        }
        if (t < 128)
            *(unsigned short*)(buf + (size_t)(side ? 129 : 0) * 136 + hci * 2) = f2bf(hv);
    };

    // ---- pipeline prologue ----
    const int h0 = hq * 4;
    LOADX(h0);
    WRITEX(xsb[0]);
    LOADX(h0 + 1);
    __syncthreads();

    for (int hh = 0; hh < 4; ++hh) {
        const int h   = h0 + hh;
        const int cur = hh & 1;

        // ---- MFMA: o-tile `wave`, 8 w-tiles of 16 ----
        f32x4 acc[8];
#pragma unroll
        for (int i = 0; i < 8; ++i) acc[i] = (f32x4){0.f, 0.f, 0.f, 0.f};
        {
            const char* bbase = xsb[cur] + col * 136 + q * 16;
#pragma unroll
            for (int wt = 0; wt < 8; ++wt) {
#pragma unroll
                for (int kk = 0; kk < 2; ++kk) {
#pragma unroll
                    for (int tap = 0; tap < 3; ++tap) {
                        const int off = (wt * 16 + tap) * 136 + kk * 64;
                        const bf16x4 lo = *(const bf16x4*)(bbase + off);
                        const bf16x4 hi = *(const bf16x4*)(bbase + off + 8);
                        const bf16x8 bfr =
                            __builtin_shufflevector(lo, hi, 0, 1, 2, 3, 4, 5, 6, 7);
                        acc[wt] = __builtin_amdgcn_mfma_f32_16x16x32_bf16(
                            afr[tap][kk], bfr, acc[wt], 0, 0, 0);
                    }
                }
            }
        }

        // ---- store y: o = g*64 + wave*16 + q*4 + r, w = wq*128 + wt*16 + col ----
        {
            float* yb = y + ((size_t)(b * C + g * 64 + wave * 16 + q * 4) * H + h) * W +
                        wq * 128 + col;
#pragma unroll
            for (int r = 0; r < 4; ++r)
#pragma unroll
                for (int wt = 0; wt < 8; ++wt)
                    yb[(size_t)r * H * W + wt * 16] = acc[wt][r];
        }

        // ---- pool over this block's 128 w, per o -> pool3p (direct write) ----
        {
            float wm[4], wsv[4];
#pragma unroll
            for (int r = 0; r < 4; ++r) { wm[r] = acc[0][r]; wsv[r] = acc[0][r]; }
#pragma unroll
            for (int wt = 1; wt < 8; ++wt)
#pragma unroll
                for (int r = 0; r < 4; ++r) {
                    wm[r]  = fmaxf(wm[r], acc[wt][r]);
                    wsv[r] += acc[wt][r];
                }
#pragma unroll
            for (int off = 8; off; off >>= 1)
#pragma unroll
                for (int r = 0; r < 4; ++r) {
                    wm[r]  = fmaxf(wm[r], __shfl_xor(wm[r], off));
                    wsv[r] += __shfl_xor(wsv[r], off);
                }
            if (col == 0) {
#pragma unroll
                for (int r = 0; r < 4; ++r) {
                    const int c = g * 64 + wave * 16 + q * 4 + r;
                    pool3p[(((size_t)wq * B + b) * 2 + 0) * (H * C) + h * C + c] = wm[r];
                    pool3p[(((size_t)wq * B + b) * 2 + 1) * (H * C) + h * C + c] = wsv[r];
                }
            }
        }
        // ---- pool over this wave's 16 o, per w -> pcm/pcs ----
        {
            float cm[8], cs[8];
#pragma unroll
            for (int wt = 0; wt < 8; ++wt) {
                cm[wt] = fmaxf(fmaxf(acc[wt][0], acc[wt][1]),
                               fmaxf(acc[wt][2], acc[wt][3]));
                cs[wt] = acc[wt][0] + acc[wt][1] + acc[wt][2] + acc[wt][3];
            }
#pragma unroll
            for (int off = 16; off <= 32; off <<= 1)
#pragma unroll
                for (int wt = 0; wt < 8; ++wt) {
                    cm[wt] = fmaxf(cm[wt], __shfl_xor(cm[wt], off));
                    cs[wt] += __shfl_xor(cs[wt], off);
                }
            if (lane < 16)
#pragma unroll
                for (int wt = 0; wt < 8; ++wt) {
                    pcm[wave * 128 + wt * 16 + col] = cm[wt];
                    pcs[wave * 128 + wt * 16 + col] = cs[wt];
                }
        }

        // ---- pipeline: write next-h LDS from regs, then issue loads 2 ahead ----
        if (hh < 3) WRITEX(xsb[cur ^ 1]);
        if (hh < 2) LOADX(h0 + hh + 2);
        __syncthreads();

        // ---- pool-C combine across 4 waves -> pool1p ----
        if (t < 128) {
            float m0 = pcm[t], s0 = pcs[t];
#pragma unroll
            for (int ot = 1; ot < 4; ++ot) {
                m0 = fmaxf(m0, pcm[ot * 128 + t]);
                s0 += pcs[ot * 128 + t];
            }
            pool1p[((size_t)(g * B + b) * 2 + 0) * (H * W) + h * W + wq * 128 + t] = m0;
            pool1p[((size_t)(g * B + b) * 2 + 1) * (H * W) + h * W + wq * 128 + t] = s0;
        }
        __syncthreads();
    }
}

// ---------------- combine pool1 partials (2 groups) -> pool1 [B,2,H,W] ----------------
__global__ __launch_bounds__(256) void combine_pool1(const float* __restrict__ p1p,
                                                     float* __restrict__ pool1) {
    const int n = blockIdx.x * 256 + threadIdx.x;   // over B*H*W/4
    const int b = n >> 12;
    const int o = (n & 4095) * 4;                   // h*W+w offset
    const float4 m0 = *(const float4*)(p1p + ((size_t)(0 * B + b) * 2 + 0) * (H * W) + o);
    const float4 m1 = *(const float4*)(p1p + ((size_t)(1 * B + b) * 2 + 0) * (H * W) + o);
    const float4 s0 = *(const float4*)(p1p + ((size_t)(0 * B + b) * 2 + 1) * (H * W) + o);
    const float4 s1 = *(const float4*)(p1p + ((size_t)(1 * B + b) * 2 + 1) * (H * W) + o);
    float4 mo, so;
    mo.x = fmaxf(m0.x, m1.x); mo.y = fmaxf(m0.y, m1.y);
    mo.z = fmaxf(m0.z, m1.z); mo.w = fmaxf(m0.w, m1.w);
    const float k = 1.f / C;
    so.x = (s0.x + s1.x) * k; so.y = (s0.y + s1.y) * k;
    so.z = (s0.z + s1.z) * k; so.w = (s0.w + s1.w) * k;
    *(float4*)(pool1 + ((size_t)(b * 2 + 0) * H * W) + o) = mo;
    *(float4*)(pool1 + ((size_t)(b * 2 + 1) * H * W) + o) = so;
}

// ---------------- combine pool3 partials (4 wq) -> pool3 [B,2,H,C] ----------------
__global__ __launch_bounds__(256) void combine_pool3(const float* __restrict__ p3p,
                                                     float* __restrict__ pool3) {
    const int n = blockIdx.x * 256 + threadIdx.x;   // over B*H*C = 65536
    const int b = n >> 12;
    const int o = n & 4095;                          // h*C + c
    float m = -INFINITY, s = 0.f;
#pragma unroll
    for (int wq = 0; wq < 4; ++wq) {
        m = fmaxf(m, p3p[(((size_t)wq * B + b) * 2 + 0) * (H * C) + o]);
        s += p3p[(((size_t)wq * B + b) * 2 + 1) * (H * C) + o];
    }
    pool3[((size_t)(b * 2 + 0) * H * C) + o] = m;
    pool3[((size_t)(b * 2 + 1) * H * C) + o] = s * (1.f / W);
}

// ---------------- pool over H -> [B,2,C,W], float4 ----------------
__global__ __launch_bounds__(256) void pool_h(const float* __restrict__ y,
                                              float* __restrict__ pool2) {
    const int n  = blockIdx.x * 256 + threadIdx.x;  // over B*C*(W/4)
    const int b  = n >> 14;
    const int c  = (n >> 7) & 127;
    const int w0 = (n & 127) << 2;
    const float* p = y + ((size_t)(b * C + c) * H) * W + w0;
    float4 m = *(const float4*)p;
    float4 s = m;
    for (int hh = 1; hh < H; ++hh) {
        const float4 v = *(const float4*)(p + (size_t)hh * W);
        m.x = fmaxf(m.x, v.x); m.y = fmaxf(m.y, v.y);
        m.z = fmaxf(m.z, v.z); m.w = fmaxf(m.w, v.w);
        s.x += v.x; s.y += v.y; s.z += v.z; s.w += v.w;
    }
    const float k = 1.f / H;
    s.x *= k; s.y *= k; s.z *= k; s.w *= k;
    *(float4*)(pool2 + ((size_t)(b * 2 + 0) * C + c) * W + w0) = m;
    *(float4*)(pool2 + ((size_t)(b * 2 + 1) * C + c) * W + w0) = s;
}

// ---------------- 7x7 conv (2->1 ch) + sigmoid, 4 outputs/thread ----------------
__global__ __launch_bounds__(256) void conv7_sig(const float* __restrict__ pin,
                                                 const float* __restrict__ wgt,
                                                 float* __restrict__ sout,
                                                 int P, int Q, int total4) {
    const int n = blockIdx.x * 256 + threadIdx.x;   // over B*P*Q/4
    if (n >= total4) return;
    const int q4   = Q >> 2;
    const int q0   = (n % q4) * 4;
    const int rest = n / q4;
    const int p    = rest % P;
    const int b    = rest / P;
    float acc0 = 0.f, acc1 = 0.f, acc2 = 0.f, acc3 = 0.f;
#pragma unroll
    for (int c2 = 0; c2 < 2; ++c2) {
#pragma unroll
        for (int i = 0; i < 7; ++i) {
            const int pp = p + i - 3;
            if (pp < 0 || pp >= P) continue;
            const float* row = pin + ((size_t)(b * 2 + c2) * P + pp) * Q;
            float win[10];
#pragma unroll
            for (int j = 0; j < 10; ++j) {
                const int qq = q0 + j - 3;
                win[j] = (qq >= 0 && qq < Q) ? row[qq] : 0.f;
            }
            const float* wr = wgt + c2 * 49 + i * 7;
#pragma unroll
            for (int j = 0; j < 7; ++j) {
                const float wv = wr[j];
                acc0 += win[j]     * wv;
                acc1 += win[j + 1] * wv;
                acc2 += win[j + 2] * wv;
                acc3 += win[j + 3] * wv;
            }
        }
    }
    float4 o;
    o.x = 1.f / (1.f + expf(-acc0));
    o.y = 1.f / (1.f + expf(-acc1));
    o.z = 1.f / (1.f + expf(-acc2));
    o.w = 1.f / (1.f + expf(-acc3));
    *(float4*)(sout + (size_t)n * 4) = o;
}

// ---------------- out = y * (s1+s2+s3)/3, in place ----------------
__global__ __launch_bounds__(256) void final_mul(float* __restrict__ y,
                                                 const float* __restrict__ s1,
                                                 const float* __restrict__ s2,
                                                 const float* __restrict__ s3) {
    const int n   = blockIdx.x * 256 + threadIdx.x;  // per float4
    const int j   = n & 127;
    const int row = n >> 7;                          // (b*C+c)*H + h
    const int h = row & 31, c = (row >> 5) & 127, b = row >> 12;
    const int w0 = j << 2;
    float4 yv = *(float4*)(y + (size_t)row * W + w0);
    const float4 v1 = *(const float4*)(s1 + ((size_t)b * H + h) * W + w0);
    const float4 v2 = *(const float4*)(s2 + ((size_t)b * C + c) * W + w0);
    const float  g3 = s3[((size_t)b * H + h) * C + c];
    const float k = 1.f / 3.f;
    float4 o;
    o.x = yv.x * (v1.x + v2.x + g3) * k;
    o.y = yv.y * (v1.y + v2.y + g3) * k;
    o.z = yv.z * (v1.z + v2.z + g3) * k;
    o.w = yv.w * (v1.w + v2.w + g3) * k;
    *(float4*)(y + (size_t)row * W + w0) = o;
}

extern "C" void kernel_launch(void* const* d_in, const int* in_sizes, int n_in,
                              void* d_out, int out_size, void* d_ws, size_t ws_size,
                              hipStream_t stream) {
    const float* x  = (const float*)d_in[0];
    const float* wg = (const float*)d_in[1];
    const float* w1 = (const float*)d_in[2];
    const float* w2 = (const float*)d_in[3];
    const float* w3 = (const float*)d_in[4];
    float* y  = (float*)d_out;       // y lives in d_out; final multiply is in-place
    float* ws = (float*)d_ws;

    // Workspace (floats). pool1p/pool3p/wT live inside pool2's region; they are
    // all dead before pool_h writes pool2 (stream-ordered).
    float* pool1p = ws;                                    // [2,B,2,H,W]  1,048,576
    float* pool3p = ws + 1048576;                          // [4,B,2,H,C]    524,288
    unsigned short* wT = (unsigned short*)(ws + 1572864);  // 24,576 bf16
    float* pool2  = ws;                                    // [B,2,C,W]    2,097,152
    float* pool1  = ws + 2097152;                          // [B,2,H,W]      524,288
    float* pool3  = ws + 2621440;                          // [B,2,H,C]      131,072
    float* s1     = ws + 2752512;                          // [B,H,W]        262,144
    float* s2     = ws + 3014656;                          // [B,C,W]      1,048,576
    float* s3     = ws + 4063232;                          // [B,H,C]         65,536

    prep_wT<<<dim3(96), 256, 0, stream>>>(wg, wT);
    conv_mfma<<<dim3(8, 8, 16), 256, 0, stream>>>(x, wT, y, pool3p, pool1p);

    combine_pool1<<<dim3((B * H * W / 4) / 256), 256, 0, stream>>>(pool1p, pool1);
    combine_pool3<<<dim3((B * H * C) / 256), 256, 0, stream>>>(pool3p, pool3);
    pool_h<<<dim3((B * C * (W / 4)) / 256), 256, 0, stream>>>(y, pool2);

    conv7_sig<<<dim3(65536 / 256), 256, 0, stream>>>(pool1, w1, s1, H, W, 65536);
    conv7_sig<<<dim3(262144 / 256), 256, 0, stream>>>(pool2, w2, s2, C, W, 262144);
    conv7_sig<<<dim3(16384 / 256), 256, 0, stream>>>(pool3, w3, s3, H, C, 16384);

    final_mul<<<dim3((B * C * H * W / 4) / 256), 256, 0, stream>>>(y, s1, s2, s3);
}

// Round 8
// 199.680 us; speedup vs baseline: 1.9776x; 1.0176x over previous
//
#include <hip/hip_runtime.h>
#include <math.h>

#define B 16
#define C 128
#define H 32
#define W 512

typedef short bf16x4 __attribute__((ext_vector_type(4)));
typedef short bf16x8 __attribute__((ext_vector_type(8)));
typedef float f32x4 __attribute__((ext_vector_type(4)));

static __device__ inline unsigned short f2bf(float f) {
    unsigned u = __builtin_bit_cast(unsigned, f);
    u += 0x7fffu + ((u >> 16) & 1u);          // RNE
    return (unsigned short)(u >> 16);
}

// ---------------- prep: wg [128][64][3] f32 -> wT [2][3][64][64] bf16 ----------------
__global__ __launch_bounds__(256) void prep_wT(const float* __restrict__ wg,
                                               unsigned short* __restrict__ wT) {
    const int e = blockIdx.x * 256 + threadIdx.x;   // 24576 total
    if (e >= 24576) return;
    const int g   = e / 12288;
    const int rem = e - g * 12288;
    const int tap = rem >> 12;
    const int o   = (rem >> 6) & 63;
    const int ci  = rem & 63;
    wT[e] = f2bf(wg[((size_t)(g * 64 + o) * 64 + ci) * 3 + tap]);
}

// ---------------- Kernel A: grouped (1x3) conv via bf16 MFMA, full-H blocks ----------
// Block = (g, wq in [0,8), b): 64 o x 64 w x ALL 32 h. 256 blocks = 1 per CU.
// 256 threads = 4 waves = 4 o-tiles. Double-buffered LDS x tile [66 rows][136 B].
// Fused: pool over H (complete -> pool2), pool over W partial (pool3p, 8-way),
// pool over C partial (pool1p, 2-way).
__global__ __launch_bounds__(256) void conv_mfma(
    const float* __restrict__ x, const unsigned short* __restrict__ wT,
    float* __restrict__ y, float* __restrict__ pool3p, float* __restrict__ pool1p,
    float* __restrict__ pool2) {
    __shared__ __align__(16) char xsb[2][66 * 136];   // 17,952 B
    __shared__ float pcm[4 * 64];                     // 1 KB
    __shared__ float pcs[4 * 64];                     // 1 KB

    const int bx = blockIdx.x;          // g*8 + wq
    const int g  = bx >> 3;
    const int wq = bx & 7;
    const int b  = blockIdx.y;
    const int t  = threadIdx.x;
    const int lane = t & 63;
    const int col  = lane & 15;
    const int q    = lane >> 4;
    const int wave = t >> 6;            // o-tile 0..3

    // ---- weight A-fragments, loaded once per block (L2-hot) ----
    const unsigned short* wA =
        wT + (size_t)g * 12288 + wave * 1024 + col * 64 + q * 8;
    bf16x8 afr[3][2];
#pragma unroll
    for (int tap = 0; tap < 3; ++tap)
#pragma unroll
        for (int kk = 0; kk < 2; ++kk)
            afr[tap][kk] = *(const bf16x8*)(wA + tap * 4096 + kk * 32);

    // ---- staging state ----
    float a[4][4];
    float hv = 0.f;
    const int w0l = (t & 15) * 4;       // local w start 0..60
    const int ci0 = (t >> 4) * 4;       // ci start 0..60
    const float* xb0 = x + (size_t)(b * C + g * 64 + ci0) * (H * W) + wq * 64 + w0l;
    const int side = (t >> 6) & 1;      // halo side (valid t<128)
    const int hci  = t & 63;
    const int gw   = wq * 64 + (side ? 64 : -1);
    const bool hvalid = (t < 128) && ((side == 0) ? (wq > 0) : (wq < 7));
    const float* xh0 = x + (size_t)(b * C + g * 64 + hci) * (H * W) + gw;

    auto LOADX = [&](int h) {
#pragma unroll
        for (int i = 0; i < 4; ++i) {
            const float4 v = *(const float4*)(xb0 + (size_t)i * (H * W) + h * W);
            a[i][0] = v.x; a[i][1] = v.y; a[i][2] = v.z; a[i][3] = v.w;
        }
        hv = hvalid ? xh0[h * W] : 0.f;
    };
    auto WRITEX = [&](char* buf) {
#pragma unroll
        for (int j = 0; j < 4; ++j) {
            unsigned p0, p1;
            asm("v_cvt_pk_bf16_f32 %0, %1, %2" : "=v"(p0) : "v"(a[0][j]), "v"(a[1][j]));
            asm("v_cvt_pk_bf16_f32 %0, %1, %2" : "=v"(p1) : "v"(a[2][j]), "v"(a[3][j]));
            uint2 pk; pk.x = p0; pk.y = p1;
            *(uint2*)(buf + (size_t)(w0l + j + 1) * 136 + ci0 * 2) = pk;
        }
        if (t < 128)
            *(unsigned short*)(buf + (size_t)(side ? 65 : 0) * 136 + hci * 2) = f2bf(hv);
    };

    // ---- pool-H accumulators (persist across h) ----
    float mH[4][4], sH[4][4];
#pragma unroll
    for (int wt = 0; wt < 4; ++wt)
#pragma unroll
        for (int r = 0; r < 4; ++r) { mH[wt][r] = -INFINITY; sH[wt][r] = 0.f; }

    // ---- pipeline prologue ----
    LOADX(0);
    WRITEX(xsb[0]);
    LOADX(1);
    __syncthreads();

    for (int h = 0; h < H; ++h) {
        const int cur = h & 1;

        // ---- MFMA: o-tile `wave`, 4 w-tiles of 16 ----
        f32x4 acc[4];
#pragma unroll
        for (int i = 0; i < 4; ++i) acc[i] = (f32x4){0.f, 0.f, 0.f, 0.f};
        {
            const char* bbase = xsb[cur] + col * 136 + q * 16;
#pragma unroll
            for (int wt = 0; wt < 4; ++wt) {
#pragma unroll
                for (int kk = 0; kk < 2; ++kk) {
#pragma unroll
                    for (int tap = 0; tap < 3; ++tap) {
                        const int off = (wt * 16 + tap) * 136 + kk * 64;
                        const bf16x4 lo = *(const bf16x4*)(bbase + off);
                        const bf16x4 hi = *(const bf16x4*)(bbase + off + 8);
                        const bf16x8 bfr =
                            __builtin_shufflevector(lo, hi, 0, 1, 2, 3, 4, 5, 6, 7);
                        acc[wt] = __builtin_amdgcn_mfma_f32_16x16x32_bf16(
                            afr[tap][kk], bfr, acc[wt], 0, 0, 0);
                    }
                }
            }
        }

        // ---- store y: o = g*64 + wave*16 + q*4 + r, w = wq*64 + wt*16 + col ----
        {
            float* yb = y + ((size_t)(b * C + g * 64 + wave * 16 + q * 4) * H + h) * W +
                        wq * 64 + col;
#pragma unroll
            for (int r = 0; r < 4; ++r)
#pragma unroll
                for (int wt = 0; wt < 4; ++wt)
                    yb[(size_t)r * H * W + wt * 16] = acc[wt][r];
        }

        // ---- pool-H accumulate (registers) ----
#pragma unroll
        for (int wt = 0; wt < 4; ++wt)
#pragma unroll
            for (int r = 0; r < 4; ++r) {
                mH[wt][r] = fmaxf(mH[wt][r], acc[wt][r]);
                sH[wt][r] += acc[wt][r];
            }

        // ---- pool over this block's 64 w, per o -> pool3p ----
        {
            float wm[4], wsv[4];
#pragma unroll
            for (int r = 0; r < 4; ++r) { wm[r] = acc[0][r]; wsv[r] = acc[0][r]; }
#pragma unroll
            for (int wt = 1; wt < 4; ++wt)
#pragma unroll
                for (int r = 0; r < 4; ++r) {
                    wm[r]  = fmaxf(wm[r], acc[wt][r]);
                    wsv[r] += acc[wt][r];
                }
#pragma unroll
            for (int off = 8; off; off >>= 1)
#pragma unroll
                for (int r = 0; r < 4; ++r) {
                    wm[r]  = fmaxf(wm[r], __shfl_xor(wm[r], off));
                    wsv[r] += __shfl_xor(wsv[r], off);
                }
            if (col == 0) {
#pragma unroll
                for (int r = 0; r < 4; ++r) {
                    const int c = g * 64 + wave * 16 + q * 4 + r;
                    pool3p[(((size_t)wq * B + b) * 2 + 0) * (H * C) + h * C + c] = wm[r];
                    pool3p[(((size_t)wq * B + b) * 2 + 1) * (H * C) + h * C + c] = wsv[r];
                }
            }
        }
        // ---- pool over this wave's 16 o, per w -> pcm/pcs ----
        {
            float cm[4], cs[4];
#pragma unroll
            for (int wt = 0; wt < 4; ++wt) {
                cm[wt] = fmaxf(fmaxf(acc[wt][0], acc[wt][1]),
                               fmaxf(acc[wt][2], acc[wt][3]));
                cs[wt] = acc[wt][0] + acc[wt][1] + acc[wt][2] + acc[wt][3];
            }
#pragma unroll
            for (int off = 16; off <= 32; off <<= 1)
#pragma unroll
                for (int wt = 0; wt < 4; ++wt) {
                    cm[wt] = fmaxf(cm[wt], __shfl_xor(cm[wt], off));
                    cs[wt] += __shfl_xor(cs[wt], off);
                }
            if (lane < 16)
#pragma unroll
                for (int wt = 0; wt < 4; ++wt) {
                    pcm[wave * 64 + wt * 16 + col] = cm[wt];
                    pcs[wave * 64 + wt * 16 + col] = cs[wt];
                }
        }

        // ---- pipeline: write next-h LDS from regs, issue loads 2 ahead ----
        if (h < H - 1) WRITEX(xsb[cur ^ 1]);
        if (h < H - 2) LOADX(h + 2);
        __syncthreads();

        // ---- pool-C combine across 4 waves -> pool1p ----
        if (t < 64) {
            float m0 = pcm[t], s0 = pcs[t];
#pragma unroll
            for (int ot = 1; ot < 4; ++ot) {
                m0 = fmaxf(m0, pcm[ot * 64 + t]);
                s0 += pcs[ot * 64 + t];
            }
            pool1p[((size_t)(g * B + b) * 2 + 0) * (H * W) + h * W + wq * 64 + t] = m0;
            pool1p[((size_t)(g * B + b) * 2 + 1) * (H * W) + h * W + wq * 64 + t] = s0;
        }
        __syncthreads();
    }

    // ---- pool-H final write -> pool2 [B,2,C,W] (complete) ----
    {
        const int o0 = g * 64 + wave * 16 + q * 4;
        const int wg0 = wq * 64 + col;
#pragma unroll
        for (int r = 0; r < 4; ++r)
#pragma unroll
            for (int wt = 0; wt < 4; ++wt) {
                pool2[((size_t)(b * 2 + 0) * C + o0 + r) * W + wg0 + wt * 16] = mH[wt][r];
                pool2[((size_t)(b * 2 + 1) * C + o0 + r) * W + wg0 + wt * 16] =
                    sH[wt][r] * (1.f / H);
            }
    }
}

// ---------------- combine pool1 partials (2 groups) -> pool1 [B,2,H,W] ----------------
__global__ __launch_bounds__(256) void combine_pool1(const float* __restrict__ p1p,
                                                     float* __restrict__ pool1) {
    const int n = blockIdx.x * 256 + threadIdx.x;   // over B*H*W/4
    const int b = n >> 12;
    const int o = (n & 4095) * 4;                   // h*W+w offset
    const float4 m0 = *(const float4*)(p1p + ((size_t)(0 * B + b) * 2 + 0) * (H * W) + o);
    const float4 m1 = *(const float4*)(p1p + ((size_t)(1 * B + b) * 2 + 0) * (H * W) + o);
    const float4 s0 = *(const float4*)(p1p + ((size_t)(0 * B + b) * 2 + 1) * (H * W) + o);
    const float4 s1 = *(const float4*)(p1p + ((size_t)(1 * B + b) * 2 + 1) * (H * W) + o);
    float4 mo, so;
    mo.x = fmaxf(m0.x, m1.x); mo.y = fmaxf(m0.y, m1.y);
    mo.z = fmaxf(m0.z, m1.z); mo.w = fmaxf(m0.w, m1.w);
    const float k = 1.f / C;
    so.x = (s0.x + s1.x) * k; so.y = (s0.y + s1.y) * k;
    so.z = (s0.z + s1.z) * k; so.w = (s0.w + s1.w) * k;
    *(float4*)(pool1 + ((size_t)(b * 2 + 0) * H * W) + o) = mo;
    *(float4*)(pool1 + ((size_t)(b * 2 + 1) * H * W) + o) = so;
}

// ---------------- combine pool3 partials (8 wq) -> pool3 [B,2,H,C] ----------------
__global__ __launch_bounds__(256) void combine_pool3(const float* __restrict__ p3p,
                                                     float* __restrict__ pool3) {
    const int n = blockIdx.x * 256 + threadIdx.x;   // over B*H*C = 65536
    const int b = n >> 12;
    const int o = n & 4095;                          // h*C + c
    float m = -INFINITY, s = 0.f;
#pragma unroll
    for (int wq = 0; wq < 8; ++wq) {
        m = fmaxf(m, p3p[(((size_t)wq * B + b) * 2 + 0) * (H * C) + o]);
        s += p3p[(((size_t)wq * B + b) * 2 + 1) * (H * C) + o];
    }
    pool3[((size_t)(b * 2 + 0) * H * C) + o] = m;
    pool3[((size_t)(b * 2 + 1) * H * C) + o] = s * (1.f / W);
}

// ---------------- 7x7 conv (2->1 ch) + sigmoid, 4 outputs/thread ----------------
__global__ __launch_bounds__(256) void conv7_sig(const float* __restrict__ pin,
                                                 const float* __restrict__ wgt,
                                                 float* __restrict__ sout,
                                                 int P, int Q, int total4) {
    const int n = blockIdx.x * 256 + threadIdx.x;   // over B*P*Q/4
    if (n >= total4) return;
    const int q4   = Q >> 2;
    const int q0   = (n % q4) * 4;
    const int rest = n / q4;
    const int p    = rest % P;
    const int b    = rest / P;
    float acc0 = 0.f, acc1 = 0.f, acc2 = 0.f, acc3 = 0.f;
#pragma unroll
    for (int c2 = 0; c2 < 2; ++c2) {
#pragma unroll
        for (int i = 0; i < 7; ++i) {
            const int pp = p + i - 3;
            if (pp < 0 || pp >= P) continue;
            const float* row = pin + ((size_t)(b * 2 + c2) * P + pp) * Q;
            float win[10];
#pragma unroll
            for (int j = 0; j < 10; ++j) {
                const int qq = q0 + j - 3;
                win[j] = (qq >= 0 && qq < Q) ? row[qq] : 0.f;
            }
            const float* wr = wgt + c2 * 49 + i * 7;
#pragma unroll
            for (int j = 0; j < 7; ++j) {
                const float wv = wr[j];
                acc0 += win[j]     * wv;
                acc1 += win[j + 1] * wv;
                acc2 += win[j + 2] * wv;
                acc3 += win[j + 3] * wv;
            }
        }
    }
    float4 o;
    o.x = 1.f / (1.f + expf(-acc0));
    o.y = 1.f / (1.f + expf(-acc1));
    o.z = 1.f / (1.f + expf(-acc2));
    o.w = 1.f / (1.f + expf(-acc3));
    *(float4*)(sout + (size_t)n * 4) = o;
}

// ---------------- out = y * (s1+s2+s3)/3, in place ----------------
__global__ __launch_bounds__(256) void final_mul(float* __restrict__ y,
                                                 const float* __restrict__ s1,
                                                 const float* __restrict__ s2,
                                                 const float* __restrict__ s3) {
    const int n   = blockIdx.x * 256 + threadIdx.x;  // per float4
    const int j   = n & 127;
    const int row = n >> 7;                          // (b*C+c)*H + h
    const int h = row & 31, c = (row >> 5) & 127, b = row >> 12;
    const int w0 = j << 2;
    float4 yv = *(float4*)(y + (size_t)row * W + w0);
    const float4 v1 = *(const float4*)(s1 + ((size_t)b * H + h) * W + w0);
    const float4 v2 = *(const float4*)(s2 + ((size_t)b * C + c) * W + w0);
    const float  g3 = s3[((size_t)b * H + h) * C + c];
    const float k = 1.f / 3.f;
    float4 o;
    o.x = yv.x * (v1.x + v2.x + g3) * k;
    o.y = yv.y * (v1.y + v2.y + g3) * k;
    o.z = yv.z * (v1.z + v2.z + g3) * k;
    o.w = yv.w * (v1.w + v2.w + g3) * k;
    *(float4*)(y + (size_t)row * W + w0) = o;
}

extern "C" void kernel_launch(void* const* d_in, const int* in_sizes, int n_in,
                              void* d_out, int out_size, void* d_ws, size_t ws_size,
                              hipStream_t stream) {
    const float* x  = (const float*)d_in[0];
    const float* wg = (const float*)d_in[1];
    const float* w1 = (const float*)d_in[2];
    const float* w2 = (const float*)d_in[3];
    const float* w3 = (const float*)d_in[4];
    float* y  = (float*)d_out;       // y lives in d_out; final multiply is in-place
    float* ws = (float*)d_ws;

    // Workspace layout (float offsets). Reuse is stream-ordered:
    //  [0,        1048576): pool1p  -> later s1 @0 (262144), s3 @262144 (65536)
    //  [1048576,  2097152): pool3p  -> later s2 @1048576 (1048576)
    //  [2097152,  4194304): pool2   (written directly by conv_mfma)
    //  [4194304,  4718592): pool1
    //  [4718592,  4849664): pool3
    //  [4849664,  4861952): wT (24576 bf16 = 12288 f32 slots)
    float* pool1p = ws;
    float* pool3p = ws + 1048576;
    float* pool2  = ws + 2097152;
    float* pool1  = ws + 4194304;
    float* pool3  = ws + 4718592;
    unsigned short* wT = (unsigned short*)(ws + 4849664);
    float* s1 = ws;
    float* s3 = ws + 262144;
    float* s2 = ws + 1048576;

    prep_wT<<<dim3(96), 256, 0, stream>>>(wg, wT);
    conv_mfma<<<dim3(16, 16), 256, 0, stream>>>(x, wT, y, pool3p, pool1p, pool2);

    combine_pool1<<<dim3((B * H * W / 4) / 256), 256, 0, stream>>>(pool1p, pool1);
    combine_pool3<<<dim3((B * H * C) / 256), 256, 0, stream>>>(pool3p, pool3);

    conv7_sig<<<dim3(65536 / 256), 256, 0, stream>>>(pool1, w1, s1, H, W, 65536);
    conv7_sig<<<dim3(262144 / 256), 256, 0, stream>>>(pool2, w2, s2, C, W, 262144);
    conv7_sig<<<dim3(16384 / 256), 256, 0, stream>>>(pool3, w3, s3, H, C, 16384);

    final_mul<<<dim3((B * C * H * W / 4) / 256), 256, 0, stream>>>(y, s1, s2, s3);
}